// Round 3
// baseline (144.802 us; speedup 1.0000x reference)
//
#include <hip/hip_runtime.h>

constexpr int N_NODES = 50000;
constexpr int KNB = 12;       // neighbors per node
constexpr int F = 128;        // F_IN == F_OUT
constexpr float ALPHA = 0.2f; // LeakyReLU slope
constexpr int BM = 256;       // nodes per block (one tile per block)
constexpr int NBLK = (N_NODES + BM - 1) / BM;   // 196 blocks, <= 256 CUs, 1 blk/CU

typedef __bf16 bf16x8 __attribute__((ext_vector_type(8)));
typedef float  f32x4  __attribute__((ext_vector_type(4)));

__device__ __forceinline__ unsigned bfr(float f) {
    // round-to-nearest-even f32 -> bf16 bits
    unsigned u = __float_as_uint(f);
    return (u + 0x7fffu + ((u >> 16) & 1u)) >> 16;
}
__device__ __forceinline__ unsigned pack2(float lo, float hi) {
    return bfr(lo) | (bfr(hi) << 16);
}
__device__ __forceinline__ float bf2f(unsigned bits16) {
    return __uint_as_float(bits16 << 16);
}

// ---------------- Kernel 0: W transpose + bf16 ----------------
// Wt[n][k] bf16, n in [0,256): n<128 -> Wself[:,n], else Wnb[:,n-128].
__global__ __launch_bounds__(256) void gat_prep(const float* __restrict__ Wself,
                                                const float* __restrict__ Wnb,
                                                unsigned* __restrict__ Wt) {
    const int gid = blockIdx.x * 256 + threadIdx.x;  // 16384 total
    const int n  = gid >> 6;
    const int kp = gid & 63;
    const float* src = (n < F) ? (Wself + n) : (Wnb + (n - F));
    const float f0 = src[(size_t)(kp * 2)     * F];
    const float f1 = src[(size_t)(kp * 2 + 1) * F];
    Wt[n * 64 + kp] = pack2(f0, f1);
}

// ---------------- Fused kernel: GEMM + grid barrier + attention ----------------
// Phase A: block owns rows [base, base+256). 8 waves x 32 rows x 256 cols via MFMA.
//   cols 0..127  = x@Wself (act_self)  -> stays in REGISTERS
//   cols 128..255= x@Wnb (h)           -> bf16 to global hb; s_in/s_out reduced+stored
// Grid barrier (manual, all 196 blocks co-resident: 128KB LDS => 1 blk/CU).
// Phase B: same wave aggregates its own 32 rows: softmax over K=12 edges per
//   16-lane group, gather hb of neighbors, out = acc_self + bias + agg (single write).
__global__ __launch_bounds__(512, 2) void gat_fused(
    const float* __restrict__ x,
    const unsigned* __restrict__ Wt,   // [256][64] u32 (bf16 pairs)
    const float* __restrict__ a,
    const float* __restrict__ bias,
    const int* __restrict__ colidx,
    const float* __restrict__ adj,
    float* __restrict__ out,
    unsigned short* __restrict__ hb,
    float* __restrict__ s_in,
    float* __restrict__ s_out,
    unsigned* __restrict__ cnt)
{
    __shared__ uint4 ldsX[BM * 16];    // 256 rows x 16 frags (8 bf16 each) = 64KB
    __shared__ uint4 ldsW[256 * 16];   // 256 n    x 16 frags             = 64KB

    const int t = threadIdx.x;
    const int base = blockIdx.x * BM;

    // ---- stage W (bf16, pre-transposed by gat_prep), 8 uint4/thread ----
    const uint4* Wt4 = reinterpret_cast<const uint4*>(Wt);
#pragma unroll
    for (int i = 0; i < 8; ++i) {
        const int idx = t + i * 512;       // n*16 + k16
        const int n   = idx >> 4;
        const int k16 = idx & 15;
        ldsW[n * 16 + (k16 ^ (n & 7))] = Wt4[idx];
    }
    // ---- stage X tile (fp32 -> bf16 pack), 8 uint4/thread ----
#pragma unroll
    for (int i = 0; i < 8; ++i) {
        const int idx = t + i * 512;       // row*16 + k16
        const int row = idx >> 4;
        const int k16 = idx & 15;
        int gr = base + row; if (gr >= N_NODES) gr = N_NODES - 1;
        const float4* xp = reinterpret_cast<const float4*>(x + (size_t)gr * F + k16 * 8);
        const float4 f0 = xp[0];
        const float4 f1 = xp[1];
        uint4 v;
        v.x = pack2(f0.x, f0.y); v.y = pack2(f0.z, f0.w);
        v.z = pack2(f1.x, f1.y); v.w = pack2(f1.z, f1.w);
        ldsX[row * 16 + (k16 ^ (row & 7))] = v;
    }
    __syncthreads();

    const int w    = t >> 6;     // wave 0..7: rows w*32..w*32+31
    const int lane = t & 63;
    const int lq   = lane >> 4;  // quad 0..3
    const int lr   = lane & 15;

    const bf16x8* fx = reinterpret_cast<const bf16x8*>(ldsX);
    const bf16x8* fw = reinterpret_cast<const bf16x8*>(ldsW);

    f32x4 acc[2][16];
#pragma unroll
    for (int mt = 0; mt < 2; ++mt)
#pragma unroll
        for (int nt = 0; nt < 16; ++nt)
            acc[mt][nt] = f32x4{0.f, 0.f, 0.f, 0.f};

#pragma unroll
    for (int s = 0; s < 4; ++s) {
        bf16x8 af[2];
#pragma unroll
        for (int mt = 0; mt < 2; ++mt) {
            const int row = w * 32 + mt * 16 + lr;
            af[mt] = fx[row * 16 + ((s * 4 + lq) ^ (row & 7))];
        }
#pragma unroll
        for (int half = 0; half < 2; ++half) {
            bf16x8 bw[8];
#pragma unroll
            for (int j = 0; j < 8; ++j) {
                const int n = half * 128 + j * 16 + lr;
                bw[j] = fw[n * 16 + ((s * 4 + lq) ^ (n & 7))];
            }
#pragma unroll
            for (int mt = 0; mt < 2; ++mt)
#pragma unroll
                for (int j = 0; j < 8; ++j)
                    acc[mt][half * 8 + j] =
                        __builtin_amdgcn_mfma_f32_16x16x32_bf16(af[mt], bw[j], acc[mt][half * 8 + j], 0, 0, 0);
        }
    }

    // ---- Phase A epilogue: h half (nt 8..15) -> hb, s_in, s_out ----
    // D mapping: value acc[mt][nt][r] belongs to row base+w*32+mt*16+lq*4+r, col nt*16+lr.
    float alo[8], ahi[8], bias_v[8];
#pragma unroll
    for (int j = 0; j < 8; ++j) {
        alo[j]    = a[j * 16 + lr];
        ahi[j]    = a[F + j * 16 + lr];
        bias_v[j] = bias[j * 16 + lr];
    }
#pragma unroll
    for (int mt = 0; mt < 2; ++mt)
#pragma unroll
        for (int r = 0; r < 4; ++r) {
            const int row = base + w * 32 + mt * 16 + lq * 4 + r;
            float pin = 0.f, pout = 0.f;
#pragma unroll
            for (int j = 0; j < 8; ++j) {
                const float v = acc[mt][8 + j][r];
                pin  = fmaf(v, alo[j], pin);
                pout = fmaf(v, ahi[j], pout);
            }
#pragma unroll
            for (int msk = 8; msk >= 1; msk >>= 1) {
                pin  += __shfl_xor(pin,  msk);
                pout += __shfl_xor(pout, msk);
            }
            if (row < N_NODES) {
#pragma unroll
                for (int j = 0; j < 8; ++j)
                    hb[(size_t)row * F + j * 16 + lr] = (unsigned short)bfr(acc[mt][8 + j][r]);
                if (lr == 0) { s_in[row] = pin; s_out[row] = pout; }
            }
        }

    // ---- grid barrier (all NBLK blocks are co-resident: 1 blk/CU, NBLK<256) ----
    __threadfence();          // release this block's hb/s writes to device scope
    __syncthreads();
    if (t == 0) {
        atomicAdd(cnt, 1u);
        while (atomicAdd(cnt, 0u) < (unsigned)NBLK) __builtin_amdgcn_s_sleep(8);
    }
    __syncthreads();
    __threadfence();          // acquire: don't read stale L1/L2 for other blocks' data

    // ---- Phase B: attention + aggregation for this wave's 32 rows ----
#pragma unroll
    for (int mt = 0; mt < 2; ++mt)
#pragma unroll
        for (int r = 0; r < 4; ++r) {
            const int row = base + w * 32 + mt * 16 + lq * 4 + r;  // uniform per 16-lane group
            const bool valid = (row < N_NODES);
            int   c  = 0;
            float av = 0.f;
            float e  = -1e30f;
            if (valid && lr < KNB) {
                c  = colidx[row * KNB + lr];
                av = adj[row * KNB + lr];
                const float ev = s_in[row] + s_out[c];
                e = ev > 0.f ? ev : ALPHA * ev;
            }
            float m = e;
#pragma unroll
            for (int msk = 8; msk >= 1; msk >>= 1) m = fmaxf(m, __shfl_xor(m, msk));
            const float p = (lr < KNB) ? __expf(e - m) : 0.f;
            float ssum = p;
#pragma unroll
            for (int msk = 8; msk >= 1; msk >>= 1) ssum += __shfl_xor(ssum, msk);
            const float att = p / ssum * av;

            float agg[8];
#pragma unroll
            for (int j = 0; j < 8; ++j) agg[j] = 0.f;
            const int gbase = lane & 48;   // group's base lane
#pragma unroll
            for (int j = 0; j < KNB; ++j) {
                const float aj = __shfl(att, gbase + j);
                const int   cj = __shfl(c,   gbase + j);
                const unsigned short* hp = hb + (size_t)cj * F + lr;
#pragma unroll
                for (int nt = 0; nt < 8; ++nt) {
                    agg[nt] = fmaf(aj, bf2f((unsigned)hp[nt * 16]), agg[nt]);
                }
            }
            if (valid) {
#pragma unroll
                for (int nt = 0; nt < 8; ++nt)
                    out[(size_t)row * F + nt * 16 + lr] = acc[mt][nt][r] + bias_v[nt] + agg[nt];
            }
        }
}

extern "C" void kernel_launch(void* const* d_in, const int* in_sizes, int n_in,
                              void* d_out, int out_size, void* d_ws, size_t ws_size,
                              hipStream_t stream) {
    const float* x     = (const float*)d_in[0];
    const float* adj   = (const float*)d_in[1];
    // d_in[2] = row: implicit (edges sorted, exactly K per node)
    const int*   col   = (const int*)d_in[3];
    const float* Wself = (const float*)d_in[4];
    const float* Wnb   = (const float*)d_in[5];
    const float* a     = (const float*)d_in[6];
    const float* bias  = (const float*)d_in[7];
    float* out = (float*)d_out;

    char* ws = (char*)d_ws;
    unsigned short* hb = (unsigned short*)ws;            // 12,800,000 B
    float* s_in  = (float*)(ws + 12800000);              // 200,000 B
    float* s_out = (float*)(ws + 13000000);              // 200,000 B
    unsigned* Wt = (unsigned*)(ws + 13200000);           // 65,536 B
    unsigned* cnt = (unsigned*)(ws + 13266944);          // 4 B (16B-aligned region)

    hipMemsetAsync(cnt, 0, 4, stream);                   // reset barrier counter (replay-safe)
    gat_prep<<<64, 256, 0, stream>>>(Wself, Wnb, Wt);
    gat_fused<<<NBLK, 512, 0, stream>>>(x, Wt, a, bias, col, adj, out, hb, s_in, s_out, cnt);
}

// Round 4
// 56.578 us; speedup vs baseline: 2.5593x; 2.5593x over previous
//
#include <hip/hip_runtime.h>

constexpr int N_NODES = 50000;
constexpr int KNB = 12;       // neighbors per node
constexpr int F = 128;        // F_IN == F_OUT
constexpr float ALPHA = 0.2f; // LeakyReLU slope
constexpr int BM = 64;        // nodes per GEMM block

typedef __bf16 bf16x8 __attribute__((ext_vector_type(8)));
typedef float  f32x4  __attribute__((ext_vector_type(4)));

__device__ __forceinline__ unsigned bfr(float f) {
    unsigned u = __float_as_uint(f);
    return (u + 0x7fffu + ((u >> 16) & 1u)) >> 16;
}
__device__ __forceinline__ unsigned pack2(float lo, float hi) {
    return bfr(lo) | (bfr(hi) << 16);
}
__device__ __forceinline__ float bf2f(unsigned bits16) {
    return __uint_as_float(bits16 << 16);
}

// ---------------- Kernel 0: W transpose + bf16 ----------------
// Wt[n][k] bf16, n in [0,256): n<128 -> Wself[:,n], else Wnb[:,n-128].
__global__ __launch_bounds__(256) void gat_prep(const float* __restrict__ Wself,
                                                const float* __restrict__ Wnb,
                                                unsigned* __restrict__ Wt) {
    const int gid = blockIdx.x * 256 + threadIdx.x;  // 16384 total
    const int n  = gid >> 6;
    const int kp = gid & 63;
    const float* src = (n < F) ? (Wself + n) : (Wnb + (n - F));
    const float f0 = src[(size_t)(kp * 2)     * F];
    const float f1 = src[(size_t)(kp * 2 + 1) * F];
    Wt[n * 64 + kp] = pack2(f0, f1);
}

// ---------------- Kernel 1: fused dual GEMM via MFMA (swapped operands) ----------------
// D = mfma(W_frag, x_frag): per lane, 4 CONSECUTIVE output columns of one node row
// -> float4 stores for out, packed-u32x2 stores for hb.
// Block: 256 thr = 4 waves. Wave w owns 64 output cols [w*64, w*64+64); all 64 rows.
//   waves 0,1: self half (cols 0..127)  -> out = acc + bias
//   waves 2,3: h half   (cols 128..255) -> hb (bf16), s_in/s_out partials
__global__ __launch_bounds__(256, 2) void gat_gemm(
    const float* __restrict__ x,
    const unsigned* __restrict__ Wt,   // [256][64] u32 (bf16 pairs)
    const float* __restrict__ a,
    const float* __restrict__ bias,
    float* __restrict__ out,
    unsigned short* __restrict__ hb,
    float* __restrict__ s_in,
    float* __restrict__ s_out)
{
    __shared__ uint4 ldsX[BM * 16];    // 64 rows x 16 frags = 16KB
    __shared__ uint4 ldsW[256 * 16];   // 256 cols x 16 frags = 64KB

    const int t = threadIdx.x;
    const int base = blockIdx.x * BM;

    // ---- stage W (bf16, pre-transposed) ----
    const uint4* Wt4 = reinterpret_cast<const uint4*>(Wt);
#pragma unroll
    for (int i = 0; i < 16; ++i) {
        const int idx = t + i * 256;       // n*16 + k16
        const int n   = idx >> 4;
        const int k16 = idx & 15;
        ldsW[n * 16 + (k16 ^ (n & 7))] = Wt4[idx];
    }
    // ---- stage X tile (fp32 -> bf16 pack) ----
#pragma unroll
    for (int i = 0; i < 4; ++i) {
        const int idx = t + i * 256;       // row*16 + k16
        const int row = idx >> 4;
        const int k16 = idx & 15;
        int gr = base + row; if (gr >= N_NODES) gr = N_NODES - 1;
        const float4* xp = reinterpret_cast<const float4*>(x + (size_t)gr * F + k16 * 8);
        const float4 f0 = xp[0];
        const float4 f1 = xp[1];
        uint4 v;
        v.x = pack2(f0.x, f0.y); v.y = pack2(f0.z, f0.w);
        v.z = pack2(f1.x, f1.y); v.w = pack2(f1.z, f1.w);
        ldsX[row * 16 + (k16 ^ (row & 7))] = v;
    }
    __syncthreads();

    const int w    = t >> 6;     // wave 0..3: cols w*64..w*64+63
    const int lane = t & 63;
    const int lq   = lane >> 4;  // quad 0..3
    const int lr   = lane & 15;

    const bf16x8* fx = reinterpret_cast<const bf16x8*>(ldsX);
    const bf16x8* fw = reinterpret_cast<const bf16x8*>(ldsW);

    f32x4 acc[4][4];             // [col-tile mt][row-tile rt]
#pragma unroll
    for (int mt = 0; mt < 4; ++mt)
#pragma unroll
        for (int rt = 0; rt < 4; ++rt)
            acc[mt][rt] = f32x4{0.f, 0.f, 0.f, 0.f};

#pragma unroll
    for (int s = 0; s < 4; ++s) {
        bf16x8 wf[4], xf[4];
#pragma unroll
        for (int mt = 0; mt < 4; ++mt) {
            const int n = w * 64 + mt * 16 + lr;
            wf[mt] = fw[n * 16 + ((s * 4 + lq) ^ (n & 7))];
        }
#pragma unroll
        for (int rt = 0; rt < 4; ++rt) {
            const int r = rt * 16 + lr;
            xf[rt] = fx[r * 16 + ((s * 4 + lq) ^ (r & 7))];
        }
#pragma unroll
        for (int mt = 0; mt < 4; ++mt)
#pragma unroll
            for (int rt = 0; rt < 4; ++rt)
                acc[mt][rt] = __builtin_amdgcn_mfma_f32_16x16x32_bf16(wf[mt], xf[rt], acc[mt][rt], 0, 0, 0);
    }

    // All LDS frag reads done before we reuse ldsX for the s-reduction buffer.
    __syncthreads();
    float* sbuf = reinterpret_cast<float*>(ldsX);  // [w-2][in|out][64 nodes] -> 256 floats

    // D mapping: acc[mt][rt][r] -> col = w*64 + mt*16 + lq*4 + r, row = base + rt*16 + lr.
    if (w < 2) {
#pragma unroll
        for (int mt = 0; mt < 4; ++mt) {
            const int col0 = w * 64 + mt * 16 + lq * 4;
            const float4 b4 = *reinterpret_cast<const float4*>(bias + col0);
#pragma unroll
            for (int rt = 0; rt < 4; ++rt) {
                const int row = base + rt * 16 + lr;
                if (row < N_NODES) {
                    const f32x4 v = acc[mt][rt];
                    float4 o{v[0] + b4.x, v[1] + b4.y, v[2] + b4.z, v[3] + b4.w};
                    *reinterpret_cast<float4*>(out + (size_t)row * F + col0) = o;
                }
            }
        }
    } else {
        float spin[4] = {0.f, 0.f, 0.f, 0.f};
        float spout[4] = {0.f, 0.f, 0.f, 0.f};
#pragma unroll
        for (int mt = 0; mt < 4; ++mt) {
            const int colh0 = (w - 2) * 64 + mt * 16 + lq * 4;  // 0..127 within h
            const float4 al = *reinterpret_cast<const float4*>(a + colh0);
            const float4 ah = *reinterpret_cast<const float4*>(a + F + colh0);
#pragma unroll
            for (int rt = 0; rt < 4; ++rt) {
                const int row = base + rt * 16 + lr;
                const f32x4 v = acc[mt][rt];
                if (row < N_NODES) {
                    uint2 pk{pack2(v[0], v[1]), pack2(v[2], v[3])};
                    *reinterpret_cast<uint2*>(hb + (size_t)row * F + colh0) = pk;
                }
                spin[rt]  = fmaf(v[0], al.x, fmaf(v[1], al.y, fmaf(v[2], al.z, fmaf(v[3], al.w, spin[rt]))));
                spout[rt] = fmaf(v[0], ah.x, fmaf(v[1], ah.y, fmaf(v[2], ah.z, fmaf(v[3], ah.w, spout[rt]))));
            }
        }
        // reduce across the 4 lq-quads (lanes with same lr)
#pragma unroll
        for (int rt = 0; rt < 4; ++rt) {
            spin[rt]  += __shfl_xor(spin[rt], 16);
            spin[rt]  += __shfl_xor(spin[rt], 32);
            spout[rt] += __shfl_xor(spout[rt], 16);
            spout[rt] += __shfl_xor(spout[rt], 32);
        }
        if (lq == 0) {  // lanes 0..15 hold the per-node totals for this wave's 64 cols
#pragma unroll
            for (int rt = 0; rt < 4; ++rt) {
                sbuf[(w - 2) * 128 + rt * 16 + lr]      = spin[rt];
                sbuf[(w - 2) * 128 + 64 + rt * 16 + lr] = spout[rt];
            }
        }
    }
    __syncthreads();
    if (t < 128) {
        const int i = t & 63;
        const int row = base + i;
        if (row < N_NODES) {
            if (t < 64) s_in[row]  = sbuf[i] + sbuf[128 + i];
            else        s_out[row] = sbuf[64 + i] + sbuf[192 + i];
        }
    }
}

// ---------------- Kernel 2: attention + aggregation ----------------
// One 64-lane wave per node. Half-wave per neighbor (2 neighbors per load instr,
// dwordx2 each = full 256B bf16 row per half). xor-32 combine, float4 out RMW.
__global__ __launch_bounds__(256) void gat_attn(
    const uint2* __restrict__ hbU2,      // h bf16: [N][32] uint2
    const float* __restrict__ s_in,
    const float* __restrict__ s_out,
    const int* __restrict__ colidx,
    const float* __restrict__ adj,
    float* __restrict__ out)
{
    const int wid  = threadIdx.x >> 6;
    const int lane = threadIdx.x & 63;
    const int node = blockIdx.x * 4 + wid;   // grid*4 == N exactly
    const int half = lane >> 5;
    const int hl   = lane & 31;

    float e = -1e30f;
    int c = 0;
    float av = 0.f;
    if (lane < KNB) {
        c  = colidx[node * KNB + lane];
        av = adj[node * KNB + lane];
        const float ev = s_in[node] + s_out[c];
        e = ev > 0.f ? ev : ALPHA * ev;
    }
    float m = e;
#pragma unroll
    for (int msk = 8; msk >= 1; msk >>= 1) m = fmaxf(m, __shfl_xor(m, msk));
    const float p = (lane < KNB) ? __expf(e - m) : 0.f;
    float ssum = p;
#pragma unroll
    for (int msk = 8; msk >= 1; msk >>= 1) ssum += __shfl_xor(ssum, msk);
    const float att = p / ssum * av;   // valid for lanes 0..15 (0 for 12..15)

    float4 acc{0.f, 0.f, 0.f, 0.f};    // features 4*hl .. 4*hl+3
    const int sbase = half * 6;
#pragma unroll
    for (int i = 0; i < 6; ++i) {
        const float aj = __shfl(att, sbase + i);
        const int   cj = __shfl(c,   sbase + i);
        const uint2 u = hbU2[(size_t)cj * 32 + hl];
        acc.x = fmaf(aj, bf2f(u.x & 0xffffu), acc.x);
        acc.y = fmaf(aj, bf2f(u.x >> 16),     acc.y);
        acc.z = fmaf(aj, bf2f(u.y & 0xffffu), acc.z);
        acc.w = fmaf(aj, bf2f(u.y >> 16),     acc.w);
    }
    // combine the two halves (neighbors 0..5 + 6..11)
    acc.x += __shfl_xor(acc.x, 32);
    acc.y += __shfl_xor(acc.y, 32);
    acc.z += __shfl_xor(acc.z, 32);
    acc.w += __shfl_xor(acc.w, 32);

    if (lane < 32) {
        float4* op = reinterpret_cast<float4*>(out + (size_t)node * F) + hl;
        float4 o = *op;
        o.x += acc.x; o.y += acc.y; o.z += acc.z; o.w += acc.w;
        *op = o;
    }
}

extern "C" void kernel_launch(void* const* d_in, const int* in_sizes, int n_in,
                              void* d_out, int out_size, void* d_ws, size_t ws_size,
                              hipStream_t stream) {
    const float* x     = (const float*)d_in[0];
    const float* adj   = (const float*)d_in[1];
    // d_in[2] = row: implicit (edges sorted, exactly K per node)
    const int*   col   = (const int*)d_in[3];
    const float* Wself = (const float*)d_in[4];
    const float* Wnb   = (const float*)d_in[5];
    const float* a     = (const float*)d_in[6];
    const float* bias  = (const float*)d_in[7];
    float* out = (float*)d_out;

    char* ws = (char*)d_ws;
    unsigned short* hb = (unsigned short*)ws;            // 12,800,000 B
    float* s_in  = (float*)(ws + 12800000);              // 200,000 B
    float* s_out = (float*)(ws + 13000000);              // 200,000 B
    unsigned* Wt = (unsigned*)(ws + 13200000);           // 65,536 B

    gat_prep<<<64, 256, 0, stream>>>(Wself, Wnb, Wt);
    gat_gemm<<<(N_NODES + BM - 1) / BM, 256, 0, stream>>>(x, Wt, a, bias, out, hb, s_in, s_out);
    gat_attn<<<N_NODES / 4, 256, 0, stream>>>((const uint2*)hb, s_in, s_out, col, adj, out);
}